// Round 5
// baseline (184.575 us; speedup 1.0000x reference)
//
#include <hip/hip_runtime.h>
#include <stdint.h>

typedef __attribute__((ext_vector_type(8))) short bh8;     // 8 bf16 (MFMA A/B frag)
typedef __attribute__((ext_vector_type(4))) float f32x4;
typedef __attribute__((ext_vector_type(16))) float f32x16; // 32x32 MFMA C/D frag
typedef unsigned int uint32;

__device__ __forceinline__ unsigned short f2bf(float f) {
  uint32 u = __builtin_bit_cast(uint32, f);
  u += 0x7fffu + ((u >> 16) & 1u);   // RNE
  return (unsigned short)(u >> 16);
}

__device__ __forceinline__ uint32 cvtpk_bf16(float lo, float hi) {
  uint32 r;
  asm("v_cvt_pk_bf16_f32 %0, %1, %2" : "=v"(r) : "v"(lo), "v"(hi));
  return r;
}

// global -> LDS direct (16B/lane). LDS dest linear; swizzle via GLOBAL source addr.
__device__ __forceinline__ void lds_load16(const void* g, void* l) {
  auto gp = (const __attribute__((address_space(1))) uint32*)(uintptr_t)(g);
  auto lp = (__attribute__((address_space(3))) uint32*)(uintptr_t)(l);
  __builtin_amdgcn_global_load_lds(gp, lp, 16, 0, 0);
}

// ---------------------------------------------------------------------------
// Transpose hidden (t,c,p) -> x_bf16[n=t*256+p][c], and W (c,d) -> Wt_bf16[d][c].
__global__ __launch_bounds__(256) void k_transpose(
    const float* __restrict__ hidden, const float* __restrict__ Wq,
    const float* __restrict__ Wk, const float* __restrict__ Wv,
    unsigned short* __restrict__ xb, unsigned short* __restrict__ wt) {
  int bid = blockIdx.x, c0 = blockIdx.y * 16, tid = threadIdx.x;
  const float* in; unsigned short* out; float scale = 1.0f;
  if (bid < 32) { in = hidden + (size_t)bid * 65536; out = xb + (size_t)bid * 65536; }
  else {
    int j = bid - 32;
    in = (j == 0) ? Wq : (j == 1 ? Wk : Wv);
    out = wt + (size_t)j * 65536;
    if (j == 0) scale = 0.0625f;   // 1/sqrt(256)
  }
  __shared__ uint32 lt[256 * 9];
  uint32 pk[8];
#pragma unroll
  for (int i = 0; i < 8; ++i) {
    float a = in[(size_t)(c0 + 2 * i) * 256 + tid] * scale;      // coalesced along p
    float b = in[(size_t)(c0 + 2 * i + 1) * 256 + tid] * scale;
    pk[i] = (uint32)f2bf(a) | ((uint32)f2bf(b) << 16);
  }
#pragma unroll
  for (int i = 0; i < 8; ++i) lt[tid * 9 + i] = pk[i];
  __syncthreads();
  int q2 = tid & 1;
#pragma unroll
  for (int rr = 0; rr < 2; ++rr) {
    int r = rr * 128 + (tid >> 1);
    uint4 v;
    v.x = lt[r * 9 + q2 * 4 + 0]; v.y = lt[r * 9 + q2 * 4 + 1];
    v.z = lt[r * 9 + q2 * 4 + 2]; v.w = lt[r * 9 + q2 * 4 + 3];
    *(uint4*)(out + (size_t)r * 256 + c0 + q2 * 8) = v;          // 16B coalesced
  }
}

// ---------------------------------------------------------------------------
// GEMM: z=0: q = x*WqT_t, z=1: k = x*WkT_t (row-major [n][d]),
//       z=2: vT[d][n] = (WvT * xT)  (operand-swapped so output is d-major).
__global__ __launch_bounds__(256, 2) void k_gemm(
    const unsigned short* __restrict__ xb, const unsigned short* __restrict__ wt,
    unsigned short* __restrict__ qb, unsigned short* __restrict__ kb,
    unsigned short* __restrict__ vtb) {
  __shared__ char lds[32768];
  char* ldsA = lds; char* ldsB = lds + 16384;
  int tid = threadIdx.x, z = blockIdx.z;
  int l = tid & 63, w = tid >> 6, g = l >> 4, r15 = l & 15;
  int wr = w >> 1, wc = w & 1;
  const unsigned short *Ag, *Bg; unsigned short* out;
  int arow0, brow0; size_t ostride;
  if (z < 2) {
    Ag = xb; arow0 = blockIdx.x * 128;
    Bg = wt + (size_t)z * 65536; brow0 = blockIdx.y * 128;
    out = z ? kb : qb; ostride = 256;
  } else {
    Ag = wt + 2 * 65536; arow0 = blockIdx.y * 128;
    Bg = xb; brow0 = blockIdx.x * 128;
    out = vtb; ostride = 8192;
  }
  f32x4 acc[4][4];
#pragma unroll
  for (int i = 0; i < 4; ++i)
#pragma unroll
    for (int j = 0; j < 4; ++j) acc[i][j] = (f32x4){0.f, 0.f, 0.f, 0.f};

  for (int kk = 0; kk < 4; ++kk) {
    int c0 = kk * 64;
    __syncthreads();
#pragma unroll
    for (int p = 0; p < 4; ++p) {     // A tile [128][64] bf16, swizzled chunks
      int off = p * 4096 + tid * 16;
      int row = off >> 7, ch = (off >> 4) & 7, sc = ch ^ (row & 7);
      lds_load16((const char*)Ag + ((size_t)(arow0 + row) * 256 + c0) * 2 + sc * 16, ldsA + off);
    }
#pragma unroll
    for (int p = 0; p < 4; ++p) {     // B tile [128][64] bf16 (col-major tile), swizzled
      int off = p * 4096 + tid * 16;
      int row = off >> 7, ch = (off >> 4) & 7, sc = ch ^ (row & 7);
      lds_load16((const char*)Bg + ((size_t)(brow0 + row) * 256 + c0) * 2 + sc * 16, ldsB + off);
    }
    __syncthreads();
#pragma unroll
    for (int ks = 0; ks < 2; ++ks) {
      bh8 af[4], bfr[4];
#pragma unroll
      for (int i = 0; i < 4; ++i) {
        int rowa = wr * 64 + i * 16 + r15;
        af[i] = *(const bh8*)(ldsA + rowa * 128 + (((ks * 4 + g) ^ (rowa & 7)) * 16));
        int rowb = wc * 64 + i * 16 + r15;
        bfr[i] = *(const bh8*)(ldsB + rowb * 128 + (((ks * 4 + g) ^ (rowb & 7)) * 16));
      }
#pragma unroll
      for (int i = 0; i < 4; ++i)
#pragma unroll
        for (int j = 0; j < 4; ++j)
          acc[i][j] = __builtin_amdgcn_mfma_f32_16x16x32_bf16(af[i], bfr[j], acc[i][j], 0, 0, 0);
    }
  }
  __syncthreads();
  // bounce C (bf16) through LDS for coalesced stores
#pragma unroll
  for (int i = 0; i < 4; ++i)
#pragma unroll
    for (int j = 0; j < 4; ++j)
#pragma unroll
      for (int r = 0; r < 4; ++r) {
        int rowl = wr * 64 + i * 16 + g * 4 + r;   // C/D: row=(l>>4)*4+reg
        int coll = wc * 64 + j * 16 + r15;         //      col=l&15
        *(unsigned short*)(lds + rowl * 256 + coll * 2) = f2bf(acc[i][j][r]);
      }
  __syncthreads();
#pragma unroll
  for (int p = 0; p < 8; ++p) {
    int off = p * 4096 + tid * 16;
    int row = off >> 8, colb = off & 255;
    *(uint4*)((char*)out + ((size_t)(arow0 + row) * ostride + (size_t)brow0) * 2 + colb) =
        *(const uint4*)(lds + off);
  }
}

// ---------------------------------------------------------------------------
// Flash attention, swapped-QK^T 32x32x16 structure (m214-style adapted to D=256).
// 4 waves x 32 q-rows (QBLK=128), KVBLK=64, KV split S-ways. LDS 128KB:
// double-buffered K[64][256]bf16 + VT[256][64]bf16, 16B-chunk XOR swizzle.
// Swapped QK^T: S^T[k][q] = mfma(A=K, B=Q) -> each lane owns ONE q-row (col=l&31),
// 32 of its 64 k-scores in-register (partner lane l^32 has the other 32).
// Softmax fully in-register; P->A-frags via v_cvt_pk_bf16_f32 + 4 shfl_xor(32).
__global__ __launch_bounds__(256, 1) void k_attn(
    const unsigned short* __restrict__ qg, const unsigned short* __restrict__ kg,
    const unsigned short* __restrict__ vtg, float* __restrict__ Op,
    float* __restrict__ mp, float* __restrict__ lp, int S, int shift, int KS) {
  extern __shared__ char smem[];
  int tid = threadIdx.x;
  int w = tid >> 6, l = tid & 63, col = l & 31, half = l >> 5;
  int bid = blockIdx.x;
  int s = (bid >> 1) & (S - 1);
  int qb = ((bid >> (1 + shift)) << 1) | (bid & 1);
  int qrow0 = qb * 128 + w * 32;

  int nt = KS >> 6, kb0 = s * KS;

  // stage one KV tile: 16 global_load_lds x 16B per thread (256 threads = 64KB)
  auto stage = [&](int buf, int kvb) {
    char* Kd = smem + buf * 65536;
    char* Vd = Kd + 32768;
#pragma unroll
    for (int p = 0; p < 8; ++p) {   // K tile [64][256]: rows 512B = 32 chunks
      int off = p * 4096 + tid * 16;
      int row = off >> 9, ch = (off >> 4) & 31;
      lds_load16((const char*)kg + (size_t)(kvb + row) * 512 + ((ch ^ (row & 7)) * 16), Kd + off);
    }
#pragma unroll
    for (int p = 0; p < 8; ++p) {   // VT tile [256][64]: rows 128B = 8 chunks
      int off = p * 4096 + tid * 16;
      int row = off >> 7, ch = (off >> 4) & 7;
      lds_load16((const char*)vtg + (size_t)row * 16384 + (size_t)kvb * 2 + ((ch ^ (row & 7)) * 16),
                 Vd + off);
    }
  };

  // Q hoisted as B-fragments: lane's q-row = qrow0+col; 16 d-slices x 8 bf16
  bh8 qf[16];
  {
    const char* qrow = (const char*)qg + (size_t)(qrow0 + col) * 512 + half * 16;
#pragma unroll
    for (int t = 0; t < 16; ++t) qf[t] = *(const bh8*)(qrow + t * 32);
  }

  stage(0, kb0);   // prologue

  f32x16 o[8];
#pragma unroll
  for (int dt = 0; dt < 8; ++dt)
#pragma unroll
    for (int i = 0; i < 16; ++i) o[dt][i] = 0.f;
  float m = -INFINITY, ls = 0.f;

  for (int kt = 0; kt < nt; ++kt) {
    int cur = kt & 1;
    if (kt + 1 < nt) {
      stage(cur ^ 1, kb0 + (kt + 1) * 64);
      asm volatile("s_waitcnt vmcnt(16)" ::: "memory");   // cur tile's 16 loads done
    } else {
      asm volatile("s_waitcnt vmcnt(0)" ::: "memory");
    }
    __builtin_amdgcn_s_barrier();
    char* Kl = smem + cur * 65536;
    char* Vl = Kl + 32768;

    // S^T = K * Q^T : A = K rows (k), B = Q cols (q); accumulate over d (16 steps)
    f32x16 sc0, sc1;
#pragma unroll
    for (int i = 0; i < 16; ++i) { sc0[i] = 0.f; sc1[i] = 0.f; }
#pragma unroll
    for (int t = 0; t < 16; ++t) {
      int r0 = col, r1 = 32 + col;
      bh8 kf0 = *(const bh8*)(Kl + r0 * 512 + (((2 * t + half) ^ (r0 & 7)) * 16));
      bh8 kf1 = *(const bh8*)(Kl + r1 * 512 + (((2 * t + half) ^ (r1 & 7)) * 16));
      sc0 = __builtin_amdgcn_mfma_f32_32x32x16_bf16(kf0, qf[t], sc0, 0, 0, 0);
      sc1 = __builtin_amdgcn_mfma_f32_32x32x16_bf16(kf1, qf[t], sc1, 0, 0, 0);
    }

    // ---- in-register online softmax (lane owns q = qrow0+col; 32 of 64 k here,
    //      partner lane l^32 has the other 32) ----
    float rm = sc0[0];
#pragma unroll
    for (int i = 1; i < 16; ++i) rm = fmaxf(rm, sc0[i]);
#pragma unroll
    for (int i = 0; i < 16; ++i) rm = fmaxf(rm, sc1[i]);
    rm = fmaxf(rm, __shfl_xor(rm, 32));
    float mn = fmaxf(m, rm);
    float scl = __expf(m - mn);
    m = mn;
    float rsum = 0.f;
#pragma unroll
    for (int i = 0; i < 16; ++i) { sc0[i] = __expf(sc0[i] - mn); rsum += sc0[i]; }
#pragma unroll
    for (int i = 0; i < 16; ++i) { sc1[i] = __expf(sc1[i] - mn); rsum += sc1[i]; }
    rsum += __shfl_xor(rsum, 32);
    ls = ls * scl + rsum;

    // O-rescale: O's q-rows live across regs -> broadcast scl per reg index
    float sclb[16];
#pragma unroll
    for (int i = 0; i < 16; ++i) {
      int qs = (i & 3) + 8 * (i >> 2) + 4 * half;   // q-row held in reg i
      sclb[i] = __shfl(scl, qs);
    }
#pragma unroll
    for (int dt = 0; dt < 8; ++dt)
#pragma unroll
      for (int i = 0; i < 16; ++i) o[dt][i] *= sclb[i];

    // ---- P -> PV A-fragments, in-register (cvt_pk + half-exchange) ----
    // reg i of sc_t holds k-row (i&3)+8*(i>>2)+4*half (+32t). Lane needs
    // k = 16ks + half*8 + j  ->  low half: own rows {0-3,16-19}, partner {4-7,20-23};
    // high: partner {8-11,24-27}, own {12-15,28-31}.
    bh8 pa[4];
#pragma unroll
    for (int t2 = 0; t2 < 2; ++t2) {
      const f32x16& p = t2 ? sc1 : sc0;
      uint32 c0 = cvtpk_bf16(p[0], p[1]),  c1 = cvtpk_bf16(p[2], p[3]);
      uint32 c2 = cvtpk_bf16(p[4], p[5]),  c3 = cvtpk_bf16(p[6], p[7]);
      uint32 c4 = cvtpk_bf16(p[8], p[9]),  c5 = cvtpk_bf16(p[10], p[11]);
      uint32 c6 = cvtpk_bf16(p[12], p[13]), c7 = cvtpk_bf16(p[14], p[15]);
      uint32 za = half ? c0 : c2, zb = half ? c1 : c3;
      uint32 zc = half ? c4 : c6, zd = half ? c5 : c7;
      za = __shfl_xor((int)za, 32); zb = __shfl_xor((int)zb, 32);
      zc = __shfl_xor((int)zc, 32); zd = __shfl_xor((int)zd, 32);
      uint4 u0, u1;
      if (half == 0) { u0 = (uint4){c0, c1, za, zb}; u1 = (uint4){c4, c5, zc, zd}; }
      else           { u0 = (uint4){za, zb, c2, c3}; u1 = (uint4){zc, zd, c6, c7}; }
      pa[2 * t2 + 0] = __builtin_bit_cast(bh8, u0);
      pa[2 * t2 + 1] = __builtin_bit_cast(bh8, u1);
    }

    // ---- PV: O[q][dv] += P * V ; B-frag from VT[dv][k] tile ----
#pragma unroll
    for (int dt = 0; dt < 8; ++dt) {
      int rv = dt * 32 + col;
#pragma unroll
      for (int ks = 0; ks < 4; ++ks) {
        bh8 vf = *(const bh8*)(Vl + rv * 128 + (((2 * ks + half) ^ (rv & 7)) * 16));
        o[dt] = __builtin_amdgcn_mfma_f32_32x32x16_bf16(pa[ks], vf, o[dt], 0, 0, 0);
      }
    }

    asm volatile("s_waitcnt lgkmcnt(0)" ::: "memory");
    __builtin_amdgcn_s_barrier();
  }

  // ---- partials: O rows = (i&3)+8*(i>>2)+4*half, col = dt*32 + (l&31) ----
#pragma unroll
  for (int i = 0; i < 16; ++i) {
    int qr = (i & 3) + 8 * (i >> 2) + 4 * half;
    float* ob = Op + ((size_t)s * 8192 + qrow0 + qr) * 256 + col;
#pragma unroll
    for (int dt = 0; dt < 8; ++dt) ob[dt * 32] = o[dt][i];
  }
  if (l < 32) {
    mp[(size_t)s * 8192 + qrow0 + col] = m;
    lp[(size_t)s * 8192 + qrow0 + col] = ls;
  }
}

// ---------------------------------------------------------------------------
// Split-K combine + normalize + output transpose to (t, d, p).
__global__ __launch_bounds__(256) void k_combine(
    const float* __restrict__ Op, const float* __restrict__ mp,
    const float* __restrict__ lp, float* __restrict__ out, int S) {
  __shared__ float wsc[4 * 256];
  __shared__ float lt[32 * 257];
  int t = blockIdx.x, dc = blockIdx.y, tid = threadIdx.x;
  {
    int n = t * 256 + tid;
    float mt = -INFINITY;
#pragma unroll 4
    for (int s = 0; s < 4; ++s)
      if (s < S) mt = fmaxf(mt, mp[(size_t)s * 8192 + n]);
    float den = 0.f;
#pragma unroll 4
    for (int s = 0; s < 4; ++s)
      if (s < S) den += __expf(mp[(size_t)s * 8192 + n] - mt) * lp[(size_t)s * 8192 + n];
    float inv = 1.0f / den;
#pragma unroll 4
    for (int s = 0; s < 4; ++s)
      if (s < S) wsc[s * 256 + tid] = __expf(mp[(size_t)s * 8192 + n] - mt) * inv;
  }
  __syncthreads();
  int dl = tid & 31, pg8 = tid >> 5;   // 32 d-lanes x 8 p-rows per pass
  for (int pg = 0; pg < 32; ++pg) {
    int p = pg * 8 + pg8;
    int n = t * 256 + p;
    float a = 0.f;
#pragma unroll 4
    for (int s = 0; s < 4; ++s)
      if (s < S) a += wsc[s * 256 + p] * Op[((size_t)s * 8192 + n) * 256 + dc * 32 + dl];
    lt[dl * 257 + p] = a;
  }
  __syncthreads();
  int d8 = tid >> 5, p0 = (tid & 31) * 8;
#pragma unroll
  for (int jj = 0; jj < 4; ++jj) {
    int dd = jj * 8 + d8;
    float4 v0, v1;
    v0.x = lt[dd * 257 + p0 + 0]; v0.y = lt[dd * 257 + p0 + 1];
    v0.z = lt[dd * 257 + p0 + 2]; v0.w = lt[dd * 257 + p0 + 3];
    v1.x = lt[dd * 257 + p0 + 4]; v1.y = lt[dd * 257 + p0 + 5];
    v1.z = lt[dd * 257 + p0 + 6]; v1.w = lt[dd * 257 + p0 + 7];
    float* ob = out + (size_t)t * 65536 + (size_t)(dc * 32 + dd) * 256 + p0;
    *(float4*)ob = v0;
    *(float4*)(ob + 4) = v1;
  }
}

// ---------------------------------------------------------------------------
extern "C" void kernel_launch(void* const* d_in, const int* in_sizes, int n_in,
                              void* d_out, int out_size, void* d_ws, size_t ws_size,
                              hipStream_t stream) {
  const float* hidden = (const float*)d_in[0];
  const float* Wq = (const float*)d_in[1];
  const float* Wk = (const float*)d_in[2];
  const float* Wv = (const float*)d_in[3];
  float* out = (float*)d_out;
  char* ws = (char*)d_ws;

  const size_t off_x  = 0;                               // x_bf16: 4MB
  const size_t off_wt = 4ull << 20;                      // 3 x 128KB
  const size_t off_q  = off_wt + 3ull * 131072;
  const size_t off_k  = off_q + 8192ull * 256 * 2;
  const size_t off_vt = off_k + 8192ull * 256 * 2;
  const size_t off_O  = off_vt + 8192ull * 256 * 2;

  int S = 4;
  {
    auto need = [&](int s) {
      return off_O + (size_t)s * 8192 * 256 * 4 + (size_t)s * 8192 * 4 * 2;
    };
    if (ws_size < need(4)) S = 2;
    if (ws_size < need(2)) S = 1;
  }
  size_t off_m = off_O + (size_t)S * 8192 * 256 * 4;
  size_t off_l = off_m + (size_t)S * 8192 * 4;

  unsigned short* xb  = (unsigned short*)(ws + off_x);
  unsigned short* wt  = (unsigned short*)(ws + off_wt);
  unsigned short* qb  = (unsigned short*)(ws + off_q);
  unsigned short* kb  = (unsigned short*)(ws + off_k);
  unsigned short* vtb = (unsigned short*)(ws + off_vt);
  float* Op = (float*)(ws + off_O);
  float* mp = (float*)(ws + off_m);
  float* lp = (float*)(ws + off_l);
  int shift = (S == 4) ? 2 : (S == 2 ? 1 : 0);
  int KS = 8192 / S;

  const int attn_lds = 131072;   // K/V double buffer only; P is in registers now
  hipFuncSetAttribute((const void*)k_attn, hipFuncAttributeMaxDynamicSharedMemorySize,
                      attn_lds);

  k_transpose<<<dim3(35, 16), dim3(256), 0, stream>>>(hidden, Wq, Wk, Wv, xb, wt);
  k_gemm<<<dim3(64, 2, 3), dim3(256), 0, stream>>>(xb, wt, qb, kb, vtb);
  k_attn<<<dim3(64 * S), dim3(256), attn_lds, stream>>>(qb, kb, vtb, Op, mp, lp, S, shift, KS);
  k_combine<<<dim3(32, 8), dim3(256), 0, stream>>>(Op, mp, lp, out, S);
}